// Round 5
// baseline (409.439 us; speedup 1.0000x reference)
//
#include <hip/hip_runtime.h>

#define NQ 8192
#define CD 128
#define NB 2
#define KNN 20
#define QB 32    // queries per block (knn kernel) -> 512 blocks = 2/CU
#define TB 128   // candidates per tile
#define LDC 136  // chi/clo row stride in f16 elems (+8 pad)
#define LDSD 132 // sd row stride in f32
#define LOSCALE 4096.0f
#define LOINV (1.0f / 4096.0f)

using f16x8 = __attribute__((ext_vector_type(8))) _Float16;
using f16x2 = __attribute__((ext_vector_type(2))) _Float16;
using f32x4 = __attribute__((ext_vector_type(4))) float;

// lgkm-only barrier: orders LDS ops across the block WITHOUT draining vmcnt,
// so in-flight global prefetch loads stay in flight across it (T14).
#define LGKM_BARRIER()                                         \
  do {                                                         \
    asm volatile("s_waitcnt lgkmcnt(0)" ::: "memory");         \
    __builtin_amdgcn_s_barrier();                              \
    asm volatile("" ::: "memory");                             \
  } while (0)

// ---------------- transpose (B,C,N) f32 -> (B,N,C) split f16 hi + scaled lo ----------------
__global__ __launch_bounds__(256) void k_transpose(const float* __restrict__ x,
                                                   _Float16* __restrict__ vhi,
                                                   _Float16* __restrict__ vlo) {
  __shared__ float tile[32][33];
  int bid = blockIdx.x;
  int ctile = bid & 3;            // CD/32 = 4
  int ntile = (bid >> 2) & 255;   // NQ/32 = 256
  int b = bid >> 10;
  int c0 = ctile << 5, n0 = ntile << 5;
  int tx = threadIdx.x & 31, ty = threadIdx.x >> 5;  // ty 0..7
  const float* xb = x + (size_t)b * CD * NQ;
  _Float16* hb = vhi + (size_t)b * NQ * CD;
  _Float16* lb = vlo + (size_t)b * NQ * CD;
#pragma unroll
  for (int i = 0; i < 4; ++i) {
    int c = ty + (i << 3);
    tile[c][tx] = xb[(size_t)(c0 + c) * NQ + n0 + tx];
  }
  __syncthreads();
#pragma unroll
  for (int i = 0; i < 4; ++i) {
    int n = ty + (i << 3);
    float v = tile[tx][n];
    _Float16 h = (_Float16)v;
    float hf = (float)h;
    _Float16 l = (_Float16)((v - hf) * LOSCALE);  // exact pow2 scale keeps lo normal
    size_t o = (size_t)(n0 + n) * CD + c0 + tx;
    hb[o] = h;
    lb[o] = l;
  }
}

// ---------------- per-row sum of squares (reads x in (B,C,N), coalesced) ----------------
__global__ __launch_bounds__(256) void k_xx(const float* __restrict__ x,
                                            float* __restrict__ xx) {
  int n = blockIdx.x * 256 + threadIdx.x;
  int b = blockIdx.y;
  const float* xb = x + (size_t)b * CD * NQ + n;
  float s = 0.f;
#pragma unroll
  for (int c = 0; c < CD; ++c) {
    float v = xb[(size_t)c * NQ];
    s += v * v;
  }
  xx[(size_t)b * NQ + n] = s;
}

// ---------------- fused split-f16 MFMA distance + exact top-20 ----------------
// 512 blocks (256 q-blocks/batch), 512 threads (8 waves), 2 blocks/CU.
// Pipeline per tile: [issue t+1 global->reg] MFMA(t) | B3 | sd write | B4 |
//                    selection(t) | B1 | reg->LDS write (t+1) | B2.
// All barriers are lgkm-only so the prefetch loads stay in flight.
__global__ __launch_bounds__(512, 4) void k_knn(const _Float16* __restrict__ vhi,
                                                const _Float16* __restrict__ vlo,
                                                const float* __restrict__ xx,
                                                int* __restrict__ idxout) {
  __shared__ char ubuf[TB * LDC * 2];
  __shared__ _Float16 clo[TB][LDC];
  __shared__ float xq[QB];
  __shared__ float xc[TB];
  auto chi = (_Float16(*)[LDC])ubuf;
  auto sd = (float(*)[LDSD])ubuf;   // aliases chi; phases are time-disjoint

  const int t = threadIdx.x;
  const int blk = blockIdx.x;
  const int b = blk >> 8;
  const int q0 = (blk & 255) * QB;
  const _Float16* hb = vhi + (size_t)b * NQ * CD;
  const _Float16* lb = vlo + (size_t)b * NQ * CD;
  const float* xb = xx + (size_t)b * NQ;

  const int lane = t & 63, w = t >> 6;
  const int strip = w & 1;    // q-row strip (16 rows)
  const int quarter = w >> 1; // candidate col quarter (32 cols)

  if (t < QB) xq[t] = xb[q0 + t];

  // persistent A fragments: row = q0+16*strip+(lane&15), k = ks*32 + (lane>>4)*8
  f16x8 ahi[4], alo[4];
  {
    int row = q0 + 16 * strip + (lane & 15);
    int kof = (lane >> 4) * 8;
    const _Float16* hrow = hb + (size_t)row * CD + kof;
    const _Float16* lrow = lb + (size_t)row * CD + kof;
#pragma unroll
    for (int ks = 0; ks < 4; ++ks) {
      ahi[ks] = *(const f16x8*)(hrow + ks * 32);
      alo[ks] = *(const f16x8*)(lrow + ks * 32);
    }
  }

  // prefetch lane mapping: chunk e = t + i*512 -> row pr+32i, col chunk pch
  const int pr = t >> 4, pch = (t & 15) * 8;
  f16x8 ph[4], pl[4];
  float pxc = 0.f;

  // prologue: stage tile 0
#pragma unroll
  for (int i = 0; i < 4; ++i) {
    int r = pr + i * 32;
    ph[i] = *(const f16x8*)(hb + (size_t)r * CD + pch);
    pl[i] = *(const f16x8*)(lb + (size_t)r * CD + pch);
  }
  if (t < TB) pxc = xb[t];
#pragma unroll
  for (int i = 0; i < 4; ++i) {
    int r = pr + i * 32;
    *(f16x8*)&chi[r][pch] = ph[i];
    *(f16x8*)&clo[r][pch] = pl[i];
  }
  if (t < TB) xc[t] = pxc;
  LGKM_BARRIER();  // B2: tile 0 staged (xq also visible)

  // top-20 state: 4 queries per wave; sorted ascending, rank r lives in lane r
  float ed[4]; int ei[4]; float tau[4];
#pragma unroll
  for (int u = 0; u < 4; ++u) { ed[u] = 3.0e38f; ei[u] = 0; tau[u] = 3.0e38f; }

  auto insert1 = [&](float& edu, int& eiu, float d, int ci) {
    float sh = __shfl_up(edu, 1);
    int shi = __shfl_up(eiu, 1);
    bool cprev = (lane > 0) && (d < sh);
    bool ccur = d < edu;
    edu = ccur ? (cprev ? sh : d) : edu;
    eiu = ccur ? (cprev ? shi : ci) : eiu;
  };

  const int NT = NQ / TB;
  for (int tile = 0; tile < NT; ++tile) {
    const int c0 = tile * TB;
    const bool more = (tile + 1 < NT);

    // issue next-tile global loads NOW; consumed after selection (latency hidden)
    if (more) {
      const int cn = c0 + TB;
#pragma unroll
      for (int i = 0; i < 4; ++i) {
        int r = cn + pr + i * 32;
        ph[i] = *(const f16x8*)(hb + (size_t)r * CD + pch);
        pl[i] = *(const f16x8*)(lb + (size_t)r * CD + pch);
      }
      if (t < TB) pxc = xb[cn + t];
    }

    // MFMA: 2 fragments (16q x 32c), passes hh -> accA, (h*lo' + lo*h') -> accB
    f32x4 accA[2], accB[2];
#pragma unroll
    for (int f = 0; f < 2; ++f) {
      accA[f] = (f32x4){0.f, 0.f, 0.f, 0.f};
      accB[f] = (f32x4){0.f, 0.f, 0.f, 0.f};
    }
    const int kof = (lane >> 4) * 8;
#pragma unroll
    for (int ks = 0; ks < 4; ++ks) {
#pragma unroll
      for (int f = 0; f < 2; ++f) {
        int c = 32 * quarter + 16 * f + (lane & 15);
        f16x8 bhi = *(const f16x8*)&chi[c][ks * 32 + kof];
        f16x8 blo = *(const f16x8*)&clo[c][ks * 32 + kof];
        accA[f] = __builtin_amdgcn_mfma_f32_16x16x32_f16(ahi[ks], bhi, accA[f], 0, 0, 0);
        accB[f] = __builtin_amdgcn_mfma_f32_16x16x32_f16(ahi[ks], blo, accB[f], 0, 0, 0);
        accB[f] = __builtin_amdgcn_mfma_f32_16x16x32_f16(alo[ks], bhi, accB[f], 0, 0, 0);
      }
    }

    LGKM_BARRIER();  // B3: all waves done reading chi -> safe to overwrite with sd

    // distances straight to sd (reference association: (xx_q + (-2*dot)) + xx_c)
#pragma unroll
    for (int f = 0; f < 2; ++f) {
      int c = 32 * quarter + 16 * f + (lane & 15);
      float xcv = xc[c];
#pragma unroll
      for (int r = 0; r < 4; ++r) {
        int qrow = 16 * strip + (lane >> 4) * 4 + r;
        float dot = accA[f][r] + accB[f][r] * LOINV;
        float tmp = xq[qrow] + (-2.0f * dot);
        sd[qrow][c] = tmp + xcv;
      }
    }
    LGKM_BARRIER();  // B4: sd ready

    // selection: wave w owns queries 4w..4w+3 over all 128 cols
#pragma unroll
    for (int u = 0; u < 4; ++u) {
      int q = 4 * w + u;
      int qg = q0 + q;
      float d0 = sd[q][lane];
      float d1 = sd[q][64 + lane];
      int cnt = 0;
      unsigned long long m0 = __ballot(d0 < tau[u] && (c0 + lane) != qg);
      while (m0) {
        int l = __builtin_ctzll(m0); m0 &= m0 - 1;
        float d = __shfl(d0, l);
        if (d < tau[u]) {
          insert1(ed[u], ei[u], d, c0 + l);
          if ((++cnt & 7) == 0) tau[u] = __shfl(ed[u], 19);
        }
      }
      tau[u] = __shfl(ed[u], 19);
      unsigned long long m1 = __ballot(d1 < tau[u] && (c0 + 64 + lane) != qg);
      while (m1) {
        int l = __builtin_ctzll(m1); m1 &= m1 - 1;
        float d = __shfl(d1, l);
        if (d < tau[u]) {
          insert1(ed[u], ei[u], d, c0 + 64 + l);
          if ((++cnt & 7) == 0) tau[u] = __shfl(ed[u], 19);
        }
      }
      tau[u] = __shfl(ed[u], 19);
    }

    if (more) {
      LGKM_BARRIER();  // B1: everyone done with sd(=chi) -> safe to restage
      // reg->LDS write of tile t+1 (vmcnt wait lands here, loads long arrived)
#pragma unroll
      for (int i = 0; i < 4; ++i) {
        int r = pr + i * 32;
        *(f16x8*)&chi[r][pch] = ph[i];
        *(f16x8*)&clo[r][pch] = pl[i];
      }
      if (t < TB) xc[t] = pxc;
      LGKM_BARRIER();  // B2: tile t+1 staged
    }
  }

  if (lane < KNN) {
#pragma unroll
    for (int u = 0; u < 4; ++u)
      idxout[(size_t)(b * NQ + q0 + 4 * w + u) * KNN + lane] = ei[u];
  }
}

// ---------------- gather 20 neighbors (hi + lo/4096), max, write (B,C,N) ----------------
__global__ __launch_bounds__(256) void k_gather(const _Float16* __restrict__ vhi,
                                                const _Float16* __restrict__ vlo,
                                                const int* __restrict__ idx,
                                                float* __restrict__ out) {
  __shared__ float tile[CD][65];
  int blk = blockIdx.x;            // 256 blocks: 64 n's each
  int b = blk >> 7;
  int n0 = (blk & 127) * 64;
  int w = threadIdx.x >> 6, lane = threadIdx.x & 63;
  const _Float16* hb = vhi + (size_t)b * NQ * CD;
  const _Float16* lb = vlo + (size_t)b * NQ * CD;
  for (int s = 0; s < 16; ++s) {
    int nl = w * 16 + s;
    const int* id = idx + (size_t)(b * NQ + n0 + nl) * KNN;
    float ma = -3.0e38f, mb = -3.0e38f;  // cols 2*lane, 2*lane+1
#pragma unroll
    for (int j = 0; j < KNN; ++j) {
      size_t ro = (size_t)id[j] * CD + 2 * lane;
      f16x2 h = *(const f16x2*)(hb + ro);
      f16x2 l = *(const f16x2*)(lb + ro);
      ma = fmaxf(ma, fmaf((float)l[0], LOINV, (float)h[0]));
      mb = fmaxf(mb, fmaf((float)l[1], LOINV, (float)h[1]));
    }
    tile[2 * lane][nl] = ma;
    tile[2 * lane + 1][nl] = mb;
  }
  __syncthreads();
  float* ob = out + (size_t)b * CD * NQ;
  for (int i = 0; i < 32; ++i) {
    int e = threadIdx.x + i * 256;   // 128 c x 64 n
    int c = e >> 6, j = e & 63;
    ob[(size_t)c * NQ + n0 + j] = tile[c][j];
  }
}

extern "C" void kernel_launch(void* const* d_in, const int* in_sizes, int n_in,
                              void* d_out, int out_size, void* d_ws, size_t ws_size,
                              hipStream_t stream) {
  const float* x = (const float*)d_in[0];  // vertex_feat (B,C,N)
  size_t velems = (size_t)NB * NQ * CD;
  _Float16* vhi = (_Float16*)d_ws;                           // 4 MB
  _Float16* vlo = vhi + velems;                              // 4 MB
  float* xx = (float*)((char*)d_ws + velems * 4);            // 64 KB
  int* idx = (int*)((char*)xx + (size_t)NB * NQ * 4);        // 1.3 MB
  float* out = (float*)d_out;

  k_transpose<<<dim3(NB * 256 * 4), dim3(256), 0, stream>>>(x, vhi, vlo);
  k_xx<<<dim3(NQ / 256, NB), dim3(256), 0, stream>>>(x, xx);
  k_knn<<<dim3(NB * NQ / QB), dim3(512), 0, stream>>>(vhi, vlo, xx, idx);
  k_gather<<<dim3(NB * NQ / 64), dim3(256), 0, stream>>>(vhi, vlo, idx, out);
}